// Round 8
// baseline (145.104 us; speedup 1.0000x reference)
//
#include <hip/hip_runtime.h>
#include <hip/hip_bf16.h>

#define DIM 2048
#define NB  64
#define KSL 4          // K-split slices for qkv GEMM (512 k per block, 2 chunks)
#define JSL 2          // j-split slices for attention

typedef short bf16x8 __attribute__((ext_vector_type(8)));
typedef short s16x4  __attribute__((ext_vector_type(4)));
typedef float f32x4  __attribute__((ext_vector_type(4)));
typedef float f32x2  __attribute__((ext_vector_type(2)));

__device__ __forceinline__ unsigned short f32_to_bf16_rne(float f) {
  unsigned u = __builtin_bit_cast(unsigned, f);
  unsigned r = u + 0x7FFF + ((u >> 16) & 1);
  return (unsigned short)(r >> 16);
}

// x -> hi/lo bf16 in MFMA-fragment order (coalesced A loads in qkv), and
// zero the dense qkv accumulator (ws is poisoned 0xAA before every launch;
// qkv_mfma accumulates into it with atomics).
__global__ __launch_bounds__(256)
void prep(const float* __restrict__ x, unsigned short* __restrict__ xrh,
          unsigned short* __restrict__ xrl, float* __restrict__ qkv) {
  const int tg = blockIdx.x * 256 + threadIdx.x;   // [0, 32768)
#pragma unroll
  for (int z = 0; z < 3; ++z)                      // 3*64*2048 floats = 3 f32x4/thr
    *(float4*)(qkv + ((size_t)z * 32768 + tg) * 4) = make_float4(0.f,0.f,0.f,0.f);

  const int b = tg >> 9;
  const int k = (tg & 511) * 4;
  float4 f = *(const float4*)(x + (size_t)b * DIM + k);
  const int mt = b >> 4, l15 = b & 15;
  const int ck = k >> 5, quad = (k >> 3) & 3, u = k & 7;
  const size_t off = (((size_t)(mt * 64 + ck) * 64) + quad * 16 + l15) * 8 + u;
  float vf[4] = {f.x, f.y, f.z, f.w};
  ushort4 h4, l4;
  unsigned short* hp = &h4.x;
  unsigned short* lp = &l4.x;
#pragma unroll
  for (int e = 0; e < 4; ++e) {
    unsigned short h = f32_to_bf16_rne(vf[e]);
    float hf = __builtin_bit_cast(float, ((unsigned)h) << 16);
    hp[e] = h;
    lp[e] = f32_to_bf16_rne(vf[e] - hf);
  }
  *(ushort4*)(xrh + off) = h4;
  *(ushort4*)(xrl + off) = l4;
}

#define WSTR 260   // LDS row stride (shorts): 130 dwords == 2 mod 32 -> 4-way max

__device__ __forceinline__ void conv_store_w(short (*wh)[WSTR], short (*wl)[WSTR],
                                             const float4* wreg, int wave, int lane) {
#pragma unroll
  for (int p = 0; p < 8; ++p) {
    const int r = p * 4 + wave;
    float wf[4] = {wreg[p].x, wreg[p].y, wreg[p].z, wreg[p].w};
    s16x4 h4, l4;
#pragma unroll
    for (int e = 0; e < 4; ++e) {
      unsigned uu = __builtin_bit_cast(unsigned, wf[e]);
      h4[e] = (short)(uu >> 16);                              // trunc hi
      float hf = __builtin_bit_cast(float, uu & 0xFFFF0000u);
      float res = wf[e] - hf;
      l4[e] = (short)(__builtin_bit_cast(unsigned, res) >> 16);  // trunc lo
    }
    *(s16x4*)&wh[r][lane * 4] = h4;
    *(s16x4*)&wl[r][lane * 4] = l4;
  }
}

// C[b][j] = sum_k x[b][k]*W[j][k].  MFMA 16x16x32 bf16, 3-term hi/lo split.
// Grid (64, KSL, 3); 512 k per block, chunk-1 W register-prefetched over
// chunk-0 compute.  Epilogue: atomicAdd into dense qkv[mat][b][j] (K-slices
// accumulate; qkv zeroed by prep) -> attn needs no reduction pass.
__global__ __launch_bounds__(256)
void qkv_mfma(const unsigned short* __restrict__ xrh,
              const unsigned short* __restrict__ xrl,
              const float* __restrict__ Wq, const float* __restrict__ Wk,
              const float* __restrict__ Wv, float* __restrict__ qkv) {
  const int mat = blockIdx.z;
  const float* __restrict__ W = (mat == 0) ? Wq : ((mat == 1) ? Wk : Wv);
  const int t = threadIdx.x;
  const int wave = t >> 6, lane = t & 63;
  const int l15 = lane & 15, quad = lane >> 4;
  const int j0 = blockIdx.x * 32;
  const int kb0 = blockIdx.y * 512;

  __shared__ __align__(16) short wh[32][WSTR];
  __shared__ __align__(16) short wl[32][WSTR];

  const int jh = wave & 1;
  const int mh = wave >> 1;
  const int frow = jh * 16 + l15;
  f32x4 acc[2] = {{0.f,0.f,0.f,0.f},{0.f,0.f,0.f,0.f}};

  float4 wa[8], wb[8];
#pragma unroll
  for (int p = 0; p < 8; ++p)
    wa[p] = *(const float4*)(W + (size_t)(j0 + p * 4 + wave) * DIM + kb0 + lane * 4);

#pragma unroll
  for (int c = 0; c < 2; ++c) {
    if (c == 0) conv_store_w(wh, wl, wa, wave, lane);
    else        conv_store_w(wh, wl, wb, wave, lane);
    if (c == 0) {
#pragma unroll
      for (int p = 0; p < 8; ++p)
        wb[p] = *(const float4*)(W + (size_t)(j0 + p * 4 + wave) * DIM +
                                 kb0 + 256 + lane * 4);   // in flight over compute
    }
    __syncthreads();

    const int ckb = blockIdx.y * 16 + c * 8;
#pragma unroll
    for (int kk = 0; kk < 8; ++kk) {
      bf16x8 whf, wlf;
      *(s16x4*)&whf       = *(const s16x4*)&wh[frow][kk * 32 + quad * 8];
      *(((s16x4*)&whf)+1) = *(const s16x4*)&wh[frow][kk * 32 + quad * 8 + 4];
      *(s16x4*)&wlf       = *(const s16x4*)&wl[frow][kk * 32 + quad * 8];
      *(((s16x4*)&wlf)+1) = *(const s16x4*)&wl[frow][kk * 32 + quad * 8 + 4];
      const int ck = ckb + kk;
#pragma unroll
      for (int u = 0; u < 2; ++u) {
        const int mt = mh * 2 + u;
        const size_t xo = (((size_t)(mt * 64 + ck)) * 64 + lane) * 8;
        bf16x8 ah = *(const bf16x8*)(xrh + xo);
        bf16x8 al = *(const bf16x8*)(xrl + xo);
        acc[u] = __builtin_amdgcn_mfma_f32_16x16x32_bf16(ah, whf, acc[u], 0, 0, 0);
        acc[u] = __builtin_amdgcn_mfma_f32_16x16x32_bf16(al, whf, acc[u], 0, 0, 0);
        acc[u] = __builtin_amdgcn_mfma_f32_16x16x32_bf16(ah, wlf, acc[u], 0, 0, 0);
      }
    }
    if (c == 0) __syncthreads();
  }

  // D layout (verified R2-R7): col(j)=lane&15, row(b)=quad*4+reg
  float* __restrict__ pb = qkv + (size_t)mat * NB * DIM + j0 + jh * 16 + l15;
#pragma unroll
  for (int u = 0; u < 2; ++u)
#pragma unroll
    for (int r = 0; r < 4; ++r) {
      const int b = (mh * 2 + u) * 16 + quad * 4 + r;
      atomicAdd(pb + (size_t)b * DIM, acc[u][r]);
    }
}

// out[b][i] partials over a 1024-j slice.  k[b,:],v[b,:] addresses depend only
// on blockIdx -> uniform -> compiler scalarizes to s_load into SGPRs (SMEM
// pipe), and the inner loop is v_mul(s,v)+v_exp+v_add+v_fmac(s,v): NO LDS,
// no per-lane VMEM -- removes the 41 us LDS-pipe bound of R5-R7.
// NO max subtraction (|c*k| <~ 29, fp32-safe; validated R4-R7).
__global__ __launch_bounds__(256)
void attn(const float* __restrict__ qkv, f32x2* __restrict__ pnd) {
  const int b = blockIdx.z, js = blockIdx.y;
  const int i = blockIdx.x * 256 + threadIdx.x;
  const float qi = qkv[(size_t)b * DIM + i];
  const float c = qi * 1.4426950408889634f;
  const float* __restrict__ kp = qkv + (size_t)(NB + b) * DIM + js * (DIM / JSL);
  const float* __restrict__ vp = qkv + (size_t)(2 * NB + b) * DIM + js * (DIM / JSL);

  float num[4] = {0.f, 0.f, 0.f, 0.f};
  float den[4] = {0.f, 0.f, 0.f, 0.f};
#pragma unroll 2
  for (int j = 0; j < DIM / JSL; j += 8) {
    float kb[8], vb[8];
#pragma unroll
    for (int u = 0; u < 8; ++u) { kb[u] = kp[j + u]; vb[u] = vp[j + u]; }
#pragma unroll
    for (int u = 0; u < 8; ++u) {
      float e = __builtin_amdgcn_exp2f(c * kb[u]);
      den[u & 3] += e;
      num[u & 3] = fmaf(e, vb[u], num[u & 3]);
    }
  }
  f32x2 nd;
  nd.x = (num[0] + num[1]) + (num[2] + num[3]);
  nd.y = (den[0] + den[1]) + (den[2] + den[3]);
  pnd[((size_t)b * JSL + js) * DIM + i] = nd;
}

__global__ __launch_bounds__(256)
void attn_fin(const f32x2* __restrict__ pnd, float* __restrict__ out) {
  const int b = blockIdx.y;
  const int i = blockIdx.x * 256 + threadIdx.x;
  float n = 0.f, d = 0.f;
#pragma unroll
  for (int s = 0; s < JSL; ++s) {
    f32x2 p = pnd[((size_t)b * JSL + s) * DIM + i];
    n += p.x; d += p.y;
  }
  out[(size_t)b * DIM + i] = n / d;
}

extern "C" void kernel_launch(void* const* d_in, const int* in_sizes, int n_in,
                              void* d_out, int out_size, void* d_ws, size_t ws_size,
                              hipStream_t stream) {
  const float* x  = (const float*)d_in[0];
  const float* Wq = (const float*)d_in[1];
  const float* Wk = (const float*)d_in[2];
  const float* Wv = (const float*)d_in[3];
  float* out = (float*)d_out;

  char* w = (char*)d_ws;
  unsigned short* xrh = (unsigned short*)w;                  // 256 KB
  unsigned short* xrl = (unsigned short*)(w + (512 << 10));  // 256 KB
  float* qkv = (float*)(w + (1 << 20));                      // 1.57 MB dense
  f32x2* pnd = (f32x2*)(w + (4 << 20));                      // 2 MB (JSL=2)

  hipLaunchKernelGGL(prep, dim3(128), dim3(256), 0, stream, x, xrh, xrl, qkv);
  hipLaunchKernelGGL(qkv_mfma, dim3(64, KSL, 3), dim3(256), 0, stream,
                     xrh, xrl, Wq, Wk, Wv, qkv);
  hipLaunchKernelGGL(attn, dim3(8, JSL, NB), dim3(256), 0, stream, qkv, pnd);
  hipLaunchKernelGGL(attn_fin, dim3(8, NB), dim3(256), 0, stream, pnd, out);
}